// Round 3
// baseline (158.560 us; speedup 1.0000x reference)
//
#include <hip/hip_runtime.h>
#include <hip/hip_bf16.h>

// out = tril((2Q - tril(QK^T)K) K^T) V per (b,h): two fused causal passes of
// Y = tril(X K^T) W  (pass0: X=Q,W=K -> o2; pass1: X=2Q-o2, W=V).
// R4: paired-strip workgroups. WG = pair (p, 31-p) of 64-row t-strips sharing
// the staged K/W tiles -> uniform MFMA work (33 strip-iters/pass), 2 MFMA per
// frag read. Grid 512 (= 2 WGs/CU exactly). bf16 MFMA 16x16x32, fp32 accum.
// R5: s-permuted GEMM1 A-reads keep P in registers (no LDS P round-trip);
//     diag-only causal mask; ldsK bit5 col-XOR keeps kf reads 2-way.
// R6: double-buffered K/W tiles -> ONE barrier per iteration; loads issued at
//     iter top, packed at iter bottom (vmcnt wait overlapped with GEMMs).
// R7: complementary co-residency pairing. Iteration count per WG is
//     NT = 2*(32-p) (34..64) -- structurally non-uniform. Old mapping gave
//     blocks i and i+256 the SAME p, and those are exactly the co-resident
//     pairs under round-robin XCD dispatch -> straggler CUs carried 2x64
//     iters while others carried 2x34. New mapping flips p in the upper grid
//     half so every CU hosts one long + one short WG: uniform 98 iters/CU.

typedef __bf16 bf16x8 __attribute__((ext_vector_type(8)));
typedef __bf16 bf16x2 __attribute__((ext_vector_type(2)));
typedef float  f32x4  __attribute__((ext_vector_type(4)));

#define MFMA16(a, b, c) __builtin_amdgcn_mfma_f32_16x16x32_bf16((a), (b), (c), 0, 0, 0)

static constexpr int S  = 2048;
static constexpr int H  = 16;
static constexpr int D  = 64;
static constexpr int RS = 3 * H * D;   // 3072 floats between consecutive s rows
static constexpr int BN = 64;          // key rows per iteration
static constexpr int LR = 72;          // row stride (u16): 64 + 8

__global__ __launch_bounds__(256, 2)
void ttt_kernel(const float* __restrict__ qkv, float* __restrict__ out)
{
    __shared__ __bf16 ldsS[128 * LR];     // Q staging -> pass-transition scratch
    __shared__ __bf16 ldsK[2][BN * LR];   // K tile [s][d ^ 32*((s>>3)&1)], x2
    __shared__ __bf16 ldsW[2][D  * LR];   // W^T [d][s ^ (d&56)], x2

    const int tid  = threadIdx.x;
    const int wv   = tid >> 6;
    const int lane = tid & 63;
    const int q    = lane >> 4;        // quad 0..3
    const int l16  = lane & 15;

    // i bits: [8:7]=bh-high, [6:3]=pair, [2:0]=bh-low  (same bh-low -> same XCD)
    // R7: co-resident blocks are (i, i+256) [round-robin XCD, 2 slots/CU];
    //     flip pair index in the upper half -> long WG shares a CU with short.
    const int i   = (int)blockIdx.x;
    const int hi2 = i >> 7;                          // 0..3
    const int pp  = (i >> 3) & 15;
    const int p   = (hi2 & 2) ? (15 - pp) : pp;      // complementary halves
    const int bh  = (i & 7) + 8 * hi2;
    const int b  = bh >> 4;
    const int h  = bh & 15;
    const int tA = 64 * p;             // light strip
    const int tB = 64 * (31 - p);      // heavy strip
    const int nA = p + 1;              // s-blocks for strip A
    const int nB = 32 - p;             // s-blocks for strip B (>= nA always)

    const float* baseQ = qkv + (size_t)b * S * RS + h * D;
    const float* baseK = baseQ + H * D;
    const float* baseV = baseQ + 2 * H * D;

    // staging coords: thread owns rows r2,r2+1 cols cb..cb+7 of a 64x64 tile
    const int r2  = (tid >> 3) * 2;
    const int cb  = (tid & 7) * 8;
    const int cbK = cb ^ (((r2 >> 3) & 1) << 5);   // ldsK bit5 col swizzle

    // ---- stage Q for both strips (128 rows) -> ldsS row-major [t][d] ----
    {
        const int r   = tid >> 1;
        const int gr  = (r < 64) ? (tA + r) : (tB + r - 64);
        const int cbq = (tid & 1) * 32;
        const float* pq = baseQ + (size_t)gr * RS + cbq;
        __bf16* dst = ldsS + r * LR + cbq;
#pragma unroll
        for (int u = 0; u < 4; ++u) {
            f32x4 f0 = *(const f32x4*)(pq + u * 8);
            f32x4 f1 = *(const f32x4*)(pq + u * 8 + 4);
            bf16x8 w;
#pragma unroll
            for (int j = 0; j < 4; ++j) { w[j] = (__bf16)f0[j]; w[4 + j] = (__bf16)f1[j]; }
            *(bf16x8*)(dst + u * 8) = w;
        }
    }

    f32x4 pk[4], pv[4];   // prefetch regs: [0..1]=row r2, [2..3]=row r2+1
    auto loadT = [&](f32x4* dst, const float* base, int s0) {
        const float* pg = base + (size_t)(s0 + r2) * RS + cb;
        dst[0] = *(const f32x4*)(pg);
        dst[1] = *(const f32x4*)(pg + 4);
        dst[2] = *(const f32x4*)(pg + RS);
        dst[3] = *(const f32x4*)(pg + RS + 4);
    };

    // commit prefetch regs -> LDS tile buffers (K always from pk; W from src)
    auto commit = [&](__bf16* K_, __bf16* W_, const f32x4* src) {
        bf16x8 w0, w1;
#pragma unroll
        for (int j = 0; j < 4; ++j) {
            w0[j] = (__bf16)pk[0][j]; w0[4 + j] = (__bf16)pk[1][j];
            w1[j] = (__bf16)pk[2][j]; w1[4 + j] = (__bf16)pk[3][j];
        }
        *(bf16x8*)(K_ + r2 * LR + cbK)       = w0;
        *(bf16x8*)(K_ + (r2 + 1) * LR + cbK) = w1;
#pragma unroll
        for (int j = 0; j < 8; ++j) {
            const int d = cb + j;
            bf16x2 w;
            w[0] = (__bf16)((j < 4) ? src[0][j & 3] : src[1][j & 3]);
            w[1] = (__bf16)((j < 4) ? src[2][j & 3] : src[3][j & 3]);
            *(bf16x2*)(W_ + d * LR + (r2 ^ (d & 56))) = w;
        }
    };

    loadT(pk, baseK, 0);   // tile 0 (pass 0: K only), in flight across Q barrier

    __syncthreads();   // Q staged

    // ---- hoist X B-frags for both strips: lane holds X[t=l16][d=kt*32+q*8+j] ----
    bf16x8 Xf[2][2];   // [strip][kt]
    const int rowA = wv * 16;
    const int rowB = 64 + wv * 16;
#pragma unroll
    for (int kt = 0; kt < 2; ++kt) {
        Xf[0][kt] = *(bf16x8*)(ldsS + (rowA + l16) * LR + kt * 32 + q * 8);
        Xf[1][kt] = *(bf16x8*)(ldsS + (rowB + l16) * LR + kt * 32 + q * 8);
    }
    __bf16* sA = ldsS + rowA * LR;     // wave-private scratch, strip A (16 rows)
    __bf16* sB = ldsS + rowB * LR;     // wave-private scratch, strip B

    // permuted K-row base: A-row m of tile mi reads physical K row
    //   (mi>>1)*32 + (m>>2)*8 + (mi&1)*4 + (m&3); per-lane part (m = l16):
    const int rp   = (l16 >> 2) * 8 + (l16 & 3);
    const int kcol = (q * 8) | (((l16 >> 2) & 1) << 5);   // disjoint bits

    const f32x4 zero4 = {0.f, 0.f, 0.f, 0.f};
    f32x4 Y[2][4];                     // [strip][nd]
#pragma unroll
    for (int st = 0; st < 2; ++st)
#pragma unroll
        for (int nd = 0; nd < 4; ++nd) Y[st][nd] = zero4;

    const int tgA = tA + wv * 16 + l16;
    const int tgB = tB + wv * 16 + l16;

    // ---- prologue: commit tile 0 into buf 0 ----
    commit(ldsK[0], ldsW[0], pk);      // vmcnt wait for pk here (one-time)
    __syncthreads();                   // buf 0 visible

    const int NT = 2 * nB;             // global iterations across both passes

    for (int u = 0; u < NT; ++u) {
        const int c    = u & 1;
        const int pass = (u >= nB) ? 1 : 0;
        const int sb   = u - (pass ? nB : 0);
        const bool actA = (sb < nA);               // block-uniform branch

        // ---- issue loads for tile u+1 (consumed by pack at iter bottom) ----
        if (u + 1 < NT) {
            const int np  = (u + 1 >= nB) ? 1 : 0;
            const int nsb = (u + 1) - (np ? nB : 0);
            loadT(pk, baseK, nsb * BN);
            if (np) loadT(pv, baseV, nsb * BN);
        }

        __bf16* K_ = ldsK[c];
        __bf16* W_ = ldsW[c];

        // ---- GEMM1-T (s-permuted), both strips ----
        // Pt[mi][r] = P[s_l][t],  s_l = (mi>>1)*32 + q*8 + (mi&1)*4 + r
        f32x4 PtA[4], PtB[4];
#pragma unroll
        for (int mi = 0; mi < 4; ++mi) { PtA[mi] = zero4; PtB[mi] = zero4; }
#pragma unroll
        for (int kt = 0; kt < 2; ++kt) {
#pragma unroll
            for (int mi = 0; mi < 4; ++mi) {
                bf16x8 kf = *(bf16x8*)(K_
                    + ((mi >> 1) * 32 + (mi & 1) * 4 + rp) * LR
                    + ((kt * 32) ^ kcol));
                PtB[mi] = MFMA16(kf, Xf[1][kt], PtB[mi]);
                if (actA) PtA[mi] = MFMA16(kf, Xf[0][kt], PtA[mi]);
            }
        }

        // ---- in-register masked cvt -> GEMM2 A-frags ----
        // af[kt][b2*4+r] = P[t=l16][s = kt*32 + q*8 + b2*4 + r] (masked)
        bf16x8 afA[2], afB[2];
        {
            const bool diagB = (sb == nB - 1);
#pragma unroll
            for (int kt = 0; kt < 2; ++kt) {
                bf16x8 a;
                if (diagB) {
#pragma unroll
                    for (int b2 = 0; b2 < 2; ++b2)
#pragma unroll
                        for (int r = 0; r < 4; ++r) {
                            const int sg = sb * BN + kt * 32 + q * 8 + b2 * 4 + r;
                            a[b2 * 4 + r] = (sg <= tgB) ? (__bf16)PtB[2 * kt + b2][r]
                                                        : (__bf16)0.0f;
                        }
                } else {
#pragma unroll
                    for (int b2 = 0; b2 < 2; ++b2)
#pragma unroll
                        for (int r = 0; r < 4; ++r)
                            a[b2 * 4 + r] = (__bf16)PtB[2 * kt + b2][r];
                }
                afB[kt] = a;
            }
            if (actA) {
                const bool diagA = (sb == nA - 1);
#pragma unroll
                for (int kt = 0; kt < 2; ++kt) {
                    bf16x8 a;
                    if (diagA) {
#pragma unroll
                        for (int b2 = 0; b2 < 2; ++b2)
#pragma unroll
                            for (int r = 0; r < 4; ++r) {
                                const int sg = sb * BN + kt * 32 + q * 8 + b2 * 4 + r;
                                a[b2 * 4 + r] = (sg <= tgA) ? (__bf16)PtA[2 * kt + b2][r]
                                                            : (__bf16)0.0f;
                            }
                    } else {
#pragma unroll
                        for (int b2 = 0; b2 < 2; ++b2)
#pragma unroll
                            for (int r = 0; r < 4; ++r)
                                a[b2 * 4 + r] = (__bf16)PtA[2 * kt + b2][r];
                    }
                    afA[kt] = a;
                }
            }
        }

        // ---- GEMM2 both strips: Y[t][d] += sum_s P[t][s] W[s][d] ----
#pragma unroll
        for (int kt = 0; kt < 2; ++kt) {
#pragma unroll
            for (int nd = 0; nd < 4; ++nd) {
                const int d = l16 + nd * 16;
                bf16x8 wf = *(bf16x8*)(W_ + d * LR + ((kt * 32 + q * 8) ^ (d & 56)));
                Y[1][nd] = MFMA16(afB[kt], wf, Y[1][nd]);
                if (actA) Y[0][nd] = MFMA16(afA[kt], wf, Y[0][nd]);
            }
        }

        // ---- pass seam / epilogue (wave-private LDS scratch or stores) ----
        if (u == nB - 1) {
            // per strip: o2 (C-layout) -> scratch plain [t][d], reread as frags,
            // Xf = 2Q - o2; then reset Y.
#pragma unroll
            for (int st = 0; st < 2; ++st) {
                __bf16* sc = (st == 0) ? sA : sB;
#pragma unroll
                for (int nd = 0; nd < 4; ++nd)
#pragma unroll
                    for (int r = 0; r < 4; ++r)
                        sc[(q * 4 + r) * LR + l16 + nd * 16] = (__bf16)Y[st][nd][r];
#pragma unroll
                for (int kt = 0; kt < 2; ++kt) {
                    bf16x8 of = *(bf16x8*)(sc + l16 * LR + kt * 32 + q * 8);
#pragma unroll
                    for (int j = 0; j < 8; ++j)
                        Xf[st][kt][j] = (__bf16)(2.0f * (float)Xf[st][kt][j] - (float)of[j]);
                }
#pragma unroll
                for (int nd = 0; nd < 4; ++nd) Y[st][nd] = zero4;
            }
        } else if (u == NT - 1) {
            // out[b][t][h][d] fp32, both strips
#pragma unroll
            for (int st = 0; st < 2; ++st) {
                const int tb = (st == 0) ? tA : tB;
#pragma unroll
                for (int nd = 0; nd < 4; ++nd)
#pragma unroll
                    for (int r = 0; r < 4; ++r) {
                        const int t = tb + wv * 16 + q * 4 + r;
                        const int d = l16 + nd * 16;
                        out[(((size_t)b * S + t) * H + h) * D + d] = Y[st][nd][r];
                    }
            }
        }

        // ---- pack tile u+1 into the other buffer; single barrier ----
        if (u + 1 < NT) {
            commit(ldsK[1 - c], ldsW[1 - c], (u + 1 >= nB) ? pv : pk);
            __syncthreads();
        }
    }
}

extern "C" void kernel_launch(void* const* d_in, const int* in_sizes, int n_in,
                              void* d_out, int out_size, void* d_ws, size_t ws_size,
                              hipStream_t stream)
{
    const float* qkv = (const float*)d_in[0];
    float* out = (float*)d_out;
    ttt_kernel<<<dim3(512), 256, 0, stream>>>(qkv, out);   // 16 pairs x 32 bh
}

// Round 5
// 152.573 us; speedup vs baseline: 1.0392x; 1.0392x over previous
//
#include <hip/hip_runtime.h>
#include <hip/hip_bf16.h>

// out = tril((2Q - tril(QK^T)K) K^T) V per (b,h): two fused causal passes of
// Y = tril(X K^T) W  (pass0: X=Q,W=K -> o2; pass1: X=2Q-o2, W=V).
// R4: paired-strip workgroups. WG = pair (p, 31-p) of 64-row t-strips sharing
// the staged K/W tiles -> uniform MFMA work, 2 MFMA per frag read. Grid 512
// (= 2 WGs/CU). bf16 MFMA 16x16x32, fp32 accum.
// R5: s-permuted GEMM1 A-reads keep P in registers (no LDS P round-trip);
//     diag-only causal mask; ldsK bit5 col-XOR keeps kf reads 2-way.
// R6: double-buffered K/W tiles -> ONE barrier per iteration; loads issued at
//     iter top, packed at iter bottom.
// R8: (a) dispatch-model-hedged complementary pairing. R7 (complement on
//     bit8, breadth-first model) was null with occupancy flat at 17.4%/25%.
//     Complement now on (bit3 ^ bit8) with pp = bits[7:4]: co-resident WGs
//     get complementary NT (sum 98) under BOTH depth-first ((i,i+8)) and
//     breadth-first ((i,i+256)) slot-filling models.
//     (b) wf reads hoisted into registers between GEMM1 and the af-cvt: wf
//     is independent of GEMM1, so the 8 b128 reads stream under the cvt VALU
//     chain instead of being latency-exposed after it.
//     (c) s_setprio(1) around MFMA clusters (2 independent WGs/CU at
//     different phases -> scheduler has role diversity to arbitrate).
// (R9 = R8 resubmitted: previous bench attempt died to a container-level
//  infrastructure failure before any dispatch; theory untested.)

typedef __bf16 bf16x8 __attribute__((ext_vector_type(8)));
typedef __bf16 bf16x2 __attribute__((ext_vector_type(2)));
typedef float  f32x4  __attribute__((ext_vector_type(4)));

#define MFMA16(a, b, c) __builtin_amdgcn_mfma_f32_16x16x32_bf16((a), (b), (c), 0, 0, 0)

static constexpr int S  = 2048;
static constexpr int H  = 16;
static constexpr int D  = 64;
static constexpr int RS = 3 * H * D;   // 3072 floats between consecutive s rows
static constexpr int BN = 64;          // key rows per iteration
static constexpr int LR = 72;          // row stride (u16): 64 + 8

__global__ __launch_bounds__(256, 2)
void ttt_kernel(const float* __restrict__ qkv, float* __restrict__ out)
{
    __shared__ __bf16 ldsS[128 * LR];     // Q staging -> pass-transition scratch
    __shared__ __bf16 ldsK[2][BN * LR];   // K tile [s][d ^ 32*((s>>3)&1)], x2
    __shared__ __bf16 ldsW[2][D  * LR];   // W^T [d][s ^ (d&56)], x2

    const int tid  = threadIdx.x;
    const int wv   = tid >> 6;
    const int lane = tid & 63;
    const int q    = lane >> 4;        // quad 0..3
    const int l16  = lane & 15;

    // R8a: hedged complementary mapping. XCD = i%8 (bits 0-2). Co-resident
    // candidates differ in bit3 (depth-first) or bit8 (breadth-first); both
    // excluded from pp, and the pair-complement flips on bit3^bit8.
    const int i   = (int)blockIdx.x;
    const int lo3 = i & 7;
    const int b3  = (i >> 3) & 1;
    const int pp  = (i >> 4) & 15;
    const int b8  = (i >> 8) & 1;
    const int bh  = lo3 | (b3 << 3) | (b8 << 4);
    const int p   = (b3 ^ b8) ? (15 - pp) : pp;
    const int b  = bh >> 4;
    const int h  = bh & 15;
    const int tA = 64 * p;             // light strip
    const int tB = 64 * (31 - p);      // heavy strip
    const int nA = p + 1;              // s-blocks for strip A
    const int nB = 32 - p;             // s-blocks for strip B (>= nA always)

    const float* baseQ = qkv + (size_t)b * S * RS + h * D;
    const float* baseK = baseQ + H * D;
    const float* baseV = baseQ + 2 * H * D;

    // staging coords: thread owns rows r2,r2+1 cols cb..cb+7 of a 64x64 tile
    const int r2  = (tid >> 3) * 2;
    const int cb  = (tid & 7) * 8;
    const int cbK = cb ^ (((r2 >> 3) & 1) << 5);   // ldsK bit5 col swizzle

    // ---- stage Q for both strips (128 rows) -> ldsS row-major [t][d] ----
    {
        const int r   = tid >> 1;
        const int gr  = (r < 64) ? (tA + r) : (tB + r - 64);
        const int cbq = (tid & 1) * 32;
        const float* pq = baseQ + (size_t)gr * RS + cbq;
        __bf16* dst = ldsS + r * LR + cbq;
#pragma unroll
        for (int u = 0; u < 4; ++u) {
            f32x4 f0 = *(const f32x4*)(pq + u * 8);
            f32x4 f1 = *(const f32x4*)(pq + u * 8 + 4);
            bf16x8 w;
#pragma unroll
            for (int j = 0; j < 4; ++j) { w[j] = (__bf16)f0[j]; w[4 + j] = (__bf16)f1[j]; }
            *(bf16x8*)(dst + u * 8) = w;
        }
    }

    f32x4 pk[4], pv[4];   // prefetch regs: [0..1]=row r2, [2..3]=row r2+1
    auto loadT = [&](f32x4* dst, const float* base, int s0) {
        const float* pg = base + (size_t)(s0 + r2) * RS + cb;
        dst[0] = *(const f32x4*)(pg);
        dst[1] = *(const f32x4*)(pg + 4);
        dst[2] = *(const f32x4*)(pg + RS);
        dst[3] = *(const f32x4*)(pg + RS + 4);
    };

    // commit prefetch regs -> LDS tile buffers (K always from pk; W from src)
    auto commit = [&](__bf16* K_, __bf16* W_, const f32x4* src) {
        bf16x8 w0, w1;
#pragma unroll
        for (int j = 0; j < 4; ++j) {
            w0[j] = (__bf16)pk[0][j]; w0[4 + j] = (__bf16)pk[1][j];
            w1[j] = (__bf16)pk[2][j]; w1[4 + j] = (__bf16)pk[3][j];
        }
        *(bf16x8*)(K_ + r2 * LR + cbK)       = w0;
        *(bf16x8*)(K_ + (r2 + 1) * LR + cbK) = w1;
#pragma unroll
        for (int j = 0; j < 8; ++j) {
            const int d = cb + j;
            bf16x2 w;
            w[0] = (__bf16)((j < 4) ? src[0][j & 3] : src[1][j & 3]);
            w[1] = (__bf16)((j < 4) ? src[2][j & 3] : src[3][j & 3]);
            *(bf16x2*)(W_ + d * LR + (r2 ^ (d & 56))) = w;
        }
    };

    loadT(pk, baseK, 0);   // tile 0 (pass 0: K only), in flight across Q barrier

    __syncthreads();   // Q staged

    // ---- hoist X B-frags for both strips: lane holds X[t=l16][d=kt*32+q*8+j] ----
    bf16x8 Xf[2][2];   // [strip][kt]
    const int rowA = wv * 16;
    const int rowB = 64 + wv * 16;
#pragma unroll
    for (int kt = 0; kt < 2; ++kt) {
        Xf[0][kt] = *(bf16x8*)(ldsS + (rowA + l16) * LR + kt * 32 + q * 8);
        Xf[1][kt] = *(bf16x8*)(ldsS + (rowB + l16) * LR + kt * 32 + q * 8);
    }
    __bf16* sA = ldsS + rowA * LR;     // wave-private scratch, strip A (16 rows)
    __bf16* sB = ldsS + rowB * LR;     // wave-private scratch, strip B

    // permuted K-row base: A-row m of tile mi reads physical K row
    //   (mi>>1)*32 + (m>>2)*8 + (mi&1)*4 + (m&3); per-lane part (m = l16):
    const int rp   = (l16 >> 2) * 8 + (l16 & 3);
    const int kcol = (q * 8) | (((l16 >> 2) & 1) << 5);   // disjoint bits

    const f32x4 zero4 = {0.f, 0.f, 0.f, 0.f};
    f32x4 Y[2][4];                     // [strip][nd]
#pragma unroll
    for (int st = 0; st < 2; ++st)
#pragma unroll
        for (int nd = 0; nd < 4; ++nd) Y[st][nd] = zero4;

    const int tgA = tA + wv * 16 + l16;
    const int tgB = tB + wv * 16 + l16;

    // ---- prologue: commit tile 0 into buf 0 ----
    commit(ldsK[0], ldsW[0], pk);      // vmcnt wait for pk here (one-time)
    __syncthreads();                   // buf 0 visible

    const int NT = 2 * nB;             // global iterations across both passes

    for (int u = 0; u < NT; ++u) {
        const int c    = u & 1;
        const int pass = (u >= nB) ? 1 : 0;
        const int sb   = u - (pass ? nB : 0);
        const bool actA = (sb < nA);               // block-uniform branch

        // ---- issue loads for tile u+1 (consumed by pack at iter bottom) ----
        if (u + 1 < NT) {
            const int np  = (u + 1 >= nB) ? 1 : 0;
            const int nsb = (u + 1) - (np ? nB : 0);
            loadT(pk, baseK, nsb * BN);
            if (np) loadT(pv, baseV, nsb * BN);
        }

        __bf16* K_ = ldsK[c];
        __bf16* W_ = ldsW[c];

        // ---- GEMM1-T (s-permuted), both strips ----
        // Pt[mi][r] = P[s_l][t],  s_l = (mi>>1)*32 + q*8 + (mi&1)*4 + r
        f32x4 PtA[4], PtB[4];
#pragma unroll
        for (int mi = 0; mi < 4; ++mi) { PtA[mi] = zero4; PtB[mi] = zero4; }
        __builtin_amdgcn_s_setprio(1);
#pragma unroll
        for (int kt = 0; kt < 2; ++kt) {
#pragma unroll
            for (int mi = 0; mi < 4; ++mi) {
                bf16x8 kf = *(bf16x8*)(K_
                    + ((mi >> 1) * 32 + (mi & 1) * 4 + rp) * LR
                    + ((kt * 32) ^ kcol));
                PtB[mi] = MFMA16(kf, Xf[1][kt], PtB[mi]);
                if (actA) PtA[mi] = MFMA16(kf, Xf[0][kt], PtA[mi]);
            }
        }
        __builtin_amdgcn_s_setprio(0);

        // ---- R8b: hoist wf reads (independent of GEMM1) -> stream under cvt ----
        bf16x8 wfr[2][4];
#pragma unroll
        for (int kt = 0; kt < 2; ++kt)
#pragma unroll
            for (int nd = 0; nd < 4; ++nd) {
                const int d = l16 + nd * 16;
                wfr[kt][nd] = *(bf16x8*)(W_ + d * LR + ((kt * 32 + q * 8) ^ (d & 56)));
            }

        // ---- in-register masked cvt -> GEMM2 A-frags ----
        // af[kt][b2*4+r] = P[t=l16][s = kt*32 + q*8 + b2*4 + r] (masked)
        bf16x8 afA[2], afB[2];
        {
            const bool diagB = (sb == nB - 1);
#pragma unroll
            for (int kt = 0; kt < 2; ++kt) {
                bf16x8 a;
                if (diagB) {
#pragma unroll
                    for (int b2 = 0; b2 < 2; ++b2)
#pragma unroll
                        for (int r = 0; r < 4; ++r) {
                            const int sg = sb * BN + kt * 32 + q * 8 + b2 * 4 + r;
                            a[b2 * 4 + r] = (sg <= tgB) ? (__bf16)PtB[2 * kt + b2][r]
                                                        : (__bf16)0.0f;
                        }
                } else {
#pragma unroll
                    for (int b2 = 0; b2 < 2; ++b2)
#pragma unroll
                        for (int r = 0; r < 4; ++r)
                            a[b2 * 4 + r] = (__bf16)PtB[2 * kt + b2][r];
                }
                afB[kt] = a;
            }
            if (actA) {
                const bool diagA = (sb == nA - 1);
#pragma unroll
                for (int kt = 0; kt < 2; ++kt) {
                    bf16x8 a;
                    if (diagA) {
#pragma unroll
                        for (int b2 = 0; b2 < 2; ++b2)
#pragma unroll
                            for (int r = 0; r < 4; ++r) {
                                const int sg = sb * BN + kt * 32 + q * 8 + b2 * 4 + r;
                                a[b2 * 4 + r] = (sg <= tgA) ? (__bf16)PtA[2 * kt + b2][r]
                                                            : (__bf16)0.0f;
                            }
                    } else {
#pragma unroll
                        for (int b2 = 0; b2 < 2; ++b2)
#pragma unroll
                            for (int r = 0; r < 4; ++r)
                                a[b2 * 4 + r] = (__bf16)PtA[2 * kt + b2][r];
                    }
                    afA[kt] = a;
                }
            }
        }

        // ---- GEMM2 both strips: Y[t][d] += sum_s P[t][s] W[s][d] ----
        __builtin_amdgcn_s_setprio(1);
#pragma unroll
        for (int kt = 0; kt < 2; ++kt) {
#pragma unroll
            for (int nd = 0; nd < 4; ++nd) {
                Y[1][nd] = MFMA16(afB[kt], wfr[kt][nd], Y[1][nd]);
                if (actA) Y[0][nd] = MFMA16(afA[kt], wfr[kt][nd], Y[0][nd]);
            }
        }
        __builtin_amdgcn_s_setprio(0);

        // ---- pass seam / epilogue (wave-private LDS scratch or stores) ----
        if (u == nB - 1) {
            // per strip: o2 (C-layout) -> scratch plain [t][d], reread as frags,
            // Xf = 2Q - o2; then reset Y.
#pragma unroll
            for (int st = 0; st < 2; ++st) {
                __bf16* sc = (st == 0) ? sA : sB;
#pragma unroll
                for (int nd = 0; nd < 4; ++nd)
#pragma unroll
                    for (int r = 0; r < 4; ++r)
                        sc[(q * 4 + r) * LR + l16 + nd * 16] = (__bf16)Y[st][nd][r];
#pragma unroll
                for (int kt = 0; kt < 2; ++kt) {
                    bf16x8 of = *(bf16x8*)(sc + l16 * LR + kt * 32 + q * 8);
#pragma unroll
                    for (int j = 0; j < 8; ++j)
                        Xf[st][kt][j] = (__bf16)(2.0f * (float)Xf[st][kt][j] - (float)of[j]);
                }
#pragma unroll
                for (int nd = 0; nd < 4; ++nd) Y[st][nd] = zero4;
            }
        } else if (u == NT - 1) {
            // out[b][t][h][d] fp32, both strips
#pragma unroll
            for (int st = 0; st < 2; ++st) {
                const int tb = (st == 0) ? tA : tB;
#pragma unroll
                for (int nd = 0; nd < 4; ++nd)
#pragma unroll
                    for (int r = 0; r < 4; ++r) {
                        const int t = tb + wv * 16 + q * 4 + r;
                        const int d = l16 + nd * 16;
                        out[(((size_t)b * S + t) * H + h) * D + d] = Y[st][nd][r];
                    }
            }
        }

        // ---- pack tile u+1 into the other buffer; single barrier ----
        if (u + 1 < NT) {
            commit(ldsK[1 - c], ldsW[1 - c], (u + 1 >= nB) ? pv : pk);
            __syncthreads();
        }
    }
}

extern "C" void kernel_launch(void* const* d_in, const int* in_sizes, int n_in,
                              void* d_out, int out_size, void* d_ws, size_t ws_size,
                              hipStream_t stream)
{
    const float* qkv = (const float*)d_in[0];
    float* out = (float*)d_out;
    ttt_kernel<<<dim3(512), 256, 0, stream>>>(qkv, out);   // 16 pairs x 32 bh
}

// Round 6
// 137.299 us; speedup vs baseline: 1.1549x; 1.1112x over previous
//
#include <hip/hip_runtime.h>
#include <hip/hip_bf16.h>

// out = tril((2Q - tril(QK^T)K) K^T) V per (b,h): two fused causal passes of
// Y = tril(X K^T) W  (pass0: X=Q,W=K -> o2; pass1: X=2Q-o2, W=V).
// R5: s-permuted GEMM1 A-reads keep P in registers (no LDS P round-trip);
//     diag-only causal mask; ldsK bit5 col-XOR keeps kf reads 2-way.
// R6: double-buffered K/W tiles -> ONE barrier per iteration; loads issued at
//     iter top, packed at iter bottom.
// R8b/c: wf reads hoisted to regs between GEMM1 and cvt; setprio around MFMA.
// R10: single-strip WGs + 3 WGs/CU + dynamic backfill. Evidence: all pipes
//     <31% busy, occupancy 17% (1.4 waves/SIMD avg) -> latency-bound with too
//     few waves; placement-pairing fixes nulled twice. New decomposition:
//     1024 WGs (32 bh x 32 strips), NT = 2(p+1) iters each.
//     - LDS 46 KB/WG (64-row Q + dbuf K/W) -> 3 WGs/CU, launch_bounds(256,3).
//     - longest strips first (p = 31 - rank): 64-iter WGs start at t=0,
//       short WGs backfill as slots free -> balance without a dispatch model.
//     - bh = i&31 -> all strips of a bh on one XCD (i%8=bh%8): K+V of 4 bh
//       = 4 MB fits the XCD L2, absorbing the extra staging re-reads.

typedef __bf16 bf16x8 __attribute__((ext_vector_type(8)));
typedef __bf16 bf16x2 __attribute__((ext_vector_type(2)));
typedef float  f32x4  __attribute__((ext_vector_type(4)));

#define MFMA16(a, b, c) __builtin_amdgcn_mfma_f32_16x16x32_bf16((a), (b), (c), 0, 0, 0)

static constexpr int S  = 2048;
static constexpr int H  = 16;
static constexpr int D  = 64;
static constexpr int RS = 3 * H * D;   // 3072 floats between consecutive s rows
static constexpr int BN = 64;          // key rows per iteration
static constexpr int LR = 72;          // row stride (u16): 64 + 8

__global__ __launch_bounds__(256, 3)
void ttt_kernel(const float* __restrict__ qkv, float* __restrict__ out)
{
    __shared__ __bf16 ldsS[64 * LR];      // Q staging -> pass-transition scratch
    __shared__ __bf16 ldsK[2][BN * LR];   // K tile [s][d ^ 32*((s>>3)&1)], x2
    __shared__ __bf16 ldsW[2][D  * LR];   // W^T [d][s ^ (d&56)], x2
    // total 46080 B -> 3 WGs/CU

    const int tid  = threadIdx.x;
    const int wv   = tid >> 6;
    const int lane = tid & 63;
    const int q    = lane >> 4;        // quad 0..3
    const int l16  = lane & 15;

    // R10 mapping: rank = i>>5 ascending => p descending (longest first);
    // bh = i&31 pins all strips of a bh to one XCD (i%8 == bh%8).
    const int i  = (int)blockIdx.x;
    const int p  = 31 - (i >> 5);      // t-strip index, 64-iter strips first
    const int bh = i & 31;
    const int b  = bh >> 4;
    const int h  = bh & 15;
    const int t0 = 64 * p;             // strip rows [t0, t0+64)
    const int nP = p + 1;              // s-blocks per pass

    const float* baseQ = qkv + (size_t)b * S * RS + h * D;
    const float* baseK = baseQ + H * D;
    const float* baseV = baseQ + 2 * H * D;

    // staging coords: thread owns rows r2,r2+1 cols cb..cb+7 of a 64x64 tile
    const int r2  = (tid >> 3) * 2;
    const int cb  = (tid & 7) * 8;
    const int cbK = cb ^ (((r2 >> 3) & 1) << 5);   // ldsK bit5 col swizzle

    // ---- stage Q for the strip (64 rows) -> ldsS row-major [t][d] ----
    {
        const int r  = tid >> 2;
        const int cq = (tid & 3) * 16;
        const float* pq = baseQ + (size_t)(t0 + r) * RS + cq;
        __bf16* dst = ldsS + r * LR + cq;
#pragma unroll
        for (int u = 0; u < 2; ++u) {
            f32x4 f0 = *(const f32x4*)(pq + u * 8);
            f32x4 f1 = *(const f32x4*)(pq + u * 8 + 4);
            bf16x8 w;
#pragma unroll
            for (int j = 0; j < 4; ++j) { w[j] = (__bf16)f0[j]; w[4 + j] = (__bf16)f1[j]; }
            *(bf16x8*)(dst + u * 8) = w;
        }
    }

    f32x4 pk[4], pv[4];   // prefetch regs: [0..1]=row r2, [2..3]=row r2+1
    auto loadT = [&](f32x4* dst, const float* base, int s0) {
        const float* pg = base + (size_t)(s0 + r2) * RS + cb;
        dst[0] = *(const f32x4*)(pg);
        dst[1] = *(const f32x4*)(pg + 4);
        dst[2] = *(const f32x4*)(pg + RS);
        dst[3] = *(const f32x4*)(pg + RS + 4);
    };

    // commit prefetch regs -> LDS tile buffers (K always from pk; W from src)
    auto commit = [&](__bf16* K_, __bf16* W_, const f32x4* src) {
        bf16x8 w0, w1;
#pragma unroll
        for (int j = 0; j < 4; ++j) {
            w0[j] = (__bf16)pk[0][j]; w0[4 + j] = (__bf16)pk[1][j];
            w1[j] = (__bf16)pk[2][j]; w1[4 + j] = (__bf16)pk[3][j];
        }
        *(bf16x8*)(K_ + r2 * LR + cbK)       = w0;
        *(bf16x8*)(K_ + (r2 + 1) * LR + cbK) = w1;
#pragma unroll
        for (int j = 0; j < 8; ++j) {
            const int d = cb + j;
            bf16x2 w;
            w[0] = (__bf16)((j < 4) ? src[0][j & 3] : src[1][j & 3]);
            w[1] = (__bf16)((j < 4) ? src[2][j & 3] : src[3][j & 3]);
            *(bf16x2*)(W_ + d * LR + (r2 ^ (d & 56))) = w;
        }
    };

    loadT(pk, baseK, 0);   // tile 0 (pass 0: K only), in flight across Q barrier

    __syncthreads();   // Q staged

    // ---- hoist X B-frags: lane holds X[t=l16][d=kt*32+q*8+j] ----
    bf16x8 Xf[2];   // [kt]
    const int row0 = wv * 16;
#pragma unroll
    for (int kt = 0; kt < 2; ++kt)
        Xf[kt] = *(bf16x8*)(ldsS + (row0 + l16) * LR + kt * 32 + q * 8);
    __bf16* sc = ldsS + row0 * LR;     // wave-private scratch (16 rows)

    // permuted K-row base: A-row m of tile mi reads physical K row
    //   (mi>>1)*32 + (m>>2)*8 + (mi&1)*4 + (m&3); per-lane part (m = l16):
    const int rp   = (l16 >> 2) * 8 + (l16 & 3);
    const int kcol = (q * 8) | (((l16 >> 2) & 1) << 5);   // disjoint bits

    const f32x4 zero4 = {0.f, 0.f, 0.f, 0.f};
    f32x4 Y[4];
#pragma unroll
    for (int nd = 0; nd < 4; ++nd) Y[nd] = zero4;

    const int tg = t0 + wv * 16 + l16;

    // ---- prologue: commit tile 0 into buf 0 ----
    commit(ldsK[0], ldsW[0], pk);      // vmcnt wait for pk here (one-time)
    __syncthreads();                   // buf 0 visible

    const int NT = 2 * nP;             // iterations across both passes

    for (int u = 0; u < NT; ++u) {
        const int c  = u & 1;
        const int sb = (u >= nP) ? (u - nP) : u;

        // ---- issue loads for tile u+1 (consumed by pack at iter bottom) ----
        if (u + 1 < NT) {
            const int np_ = (u + 1 >= nP) ? 1 : 0;
            const int nsb = (u + 1) - (np_ ? nP : 0);
            loadT(pk, baseK, nsb * BN);
            if (np_) loadT(pv, baseV, nsb * BN);
        }

        __bf16* K_ = ldsK[c];
        __bf16* W_ = ldsW[c];

        // ---- GEMM1-T (s-permuted): Pt[mi][r] = P[s_l][t],
        //      s_l = (mi>>1)*32 + q*8 + (mi&1)*4 + r
        f32x4 Pt[4];
#pragma unroll
        for (int mi = 0; mi < 4; ++mi) Pt[mi] = zero4;
        __builtin_amdgcn_s_setprio(1);
#pragma unroll
        for (int kt = 0; kt < 2; ++kt) {
#pragma unroll
            for (int mi = 0; mi < 4; ++mi) {
                bf16x8 kf = *(bf16x8*)(K_
                    + ((mi >> 1) * 32 + (mi & 1) * 4 + rp) * LR
                    + ((kt * 32) ^ kcol));
                Pt[mi] = MFMA16(kf, Xf[kt], Pt[mi]);
            }
        }
        __builtin_amdgcn_s_setprio(0);

        // ---- hoist wf reads (independent of GEMM1) -> stream under cvt ----
        bf16x8 wfr[2][4];
#pragma unroll
        for (int kt = 0; kt < 2; ++kt)
#pragma unroll
            for (int nd = 0; nd < 4; ++nd) {
                const int d = l16 + nd * 16;
                wfr[kt][nd] = *(bf16x8*)(W_ + d * LR + ((kt * 32 + q * 8) ^ (d & 56)));
            }

        // ---- in-register masked cvt -> GEMM2 A-frags ----
        // af[kt][b2*4+r] = P[t=l16][s = kt*32 + q*8 + b2*4 + r] (masked)
        bf16x8 af[2];
        {
            const bool diag = (sb == nP - 1);
#pragma unroll
            for (int kt = 0; kt < 2; ++kt) {
                bf16x8 a;
                if (diag) {
#pragma unroll
                    for (int b2 = 0; b2 < 2; ++b2)
#pragma unroll
                        for (int r = 0; r < 4; ++r) {
                            const int sg = sb * BN + kt * 32 + q * 8 + b2 * 4 + r;
                            a[b2 * 4 + r] = (sg <= tg) ? (__bf16)Pt[2 * kt + b2][r]
                                                       : (__bf16)0.0f;
                        }
                } else {
#pragma unroll
                    for (int b2 = 0; b2 < 2; ++b2)
#pragma unroll
                        for (int r = 0; r < 4; ++r)
                            a[b2 * 4 + r] = (__bf16)Pt[2 * kt + b2][r];
                }
                af[kt] = a;
            }
        }

        // ---- GEMM2: Y[t][d] += sum_s P[t][s] W[s][d] ----
        __builtin_amdgcn_s_setprio(1);
#pragma unroll
        for (int kt = 0; kt < 2; ++kt)
#pragma unroll
            for (int nd = 0; nd < 4; ++nd)
                Y[nd] = MFMA16(af[kt], wfr[kt][nd], Y[nd]);
        __builtin_amdgcn_s_setprio(0);

        // ---- pass seam / epilogue (wave-private LDS scratch or stores) ----
        if (u == nP - 1) {
            // o2 (C-layout) -> scratch plain [t][d], reread as frags,
            // Xf = 2Q - o2; then reset Y.
#pragma unroll
            for (int nd = 0; nd < 4; ++nd)
#pragma unroll
                for (int r = 0; r < 4; ++r)
                    sc[(q * 4 + r) * LR + l16 + nd * 16] = (__bf16)Y[nd][r];
#pragma unroll
            for (int kt = 0; kt < 2; ++kt) {
                bf16x8 of = *(bf16x8*)(sc + l16 * LR + kt * 32 + q * 8);
#pragma unroll
                for (int j = 0; j < 8; ++j)
                    Xf[kt][j] = (__bf16)(2.0f * (float)Xf[kt][j] - (float)of[j]);
            }
#pragma unroll
            for (int nd = 0; nd < 4; ++nd) Y[nd] = zero4;
        } else if (u == NT - 1) {
            // out[b][t][h][d] fp32
#pragma unroll
            for (int nd = 0; nd < 4; ++nd)
#pragma unroll
                for (int r = 0; r < 4; ++r) {
                    const int t = t0 + wv * 16 + q * 4 + r;
                    const int d = l16 + nd * 16;
                    out[(((size_t)b * S + t) * H + h) * D + d] = Y[nd][r];
                }
        }

        // ---- pack tile u+1 into the other buffer; single barrier ----
        if (u + 1 < NT) {
            commit(ldsK[1 - c], ldsW[1 - c], (u + 1 >= nP) ? pv : pk);
            __syncthreads();
        }
    }
}

extern "C" void kernel_launch(void* const* d_in, const int* in_sizes, int n_in,
                              void* d_out, int out_size, void* d_ws, size_t ws_size,
                              hipStream_t stream)
{
    const float* qkv = (const float*)d_in[0];
    float* out = (float*)d_out;
    ttt_kernel<<<dim3(1024), 256, 0, stream>>>(qkv, out);   // 32 strips x 32 bh
}